// Round 1
// baseline (435.379 us; speedup 1.0000x reference)
//
#include <hip/hip_runtime.h>

typedef unsigned short u16;
typedef __attribute__((ext_vector_type(8))) short short8;
typedef __attribute__((ext_vector_type(4))) float f32x4;

#define D_DIM   1024
#define ROWS    32768   // B*T = 4*8192
#define T_DIM   8192

__device__ __forceinline__ float bf2f(u16 u) {
    union { unsigned int i; float f; } c; c.i = ((unsigned int)u) << 16; return c.f;
}
__device__ __forceinline__ u16 f2bf(float f) {
    union { float f; unsigned int i; } c; c.f = f;
    unsigned int r = c.i + 0x7FFF + ((c.i >> 16) & 1);   // RNE
    return (u16)(r >> 16);
}

#define GLL16(gp, lp) \
    __builtin_amdgcn_global_load_lds((const __attribute__((address_space(1))) void*)(gp), \
                                     (__attribute__((address_space(3))) void*)(lp), 16, 0, 0)

// ---------------- Kernel 0: x fp32 -> xb bf16 ----------------
__global__ void convert_x(const float* __restrict__ x, u16* __restrict__ xb) {
    size_t idx = ((size_t)blockIdx.x * 256 + threadIdx.x) * 8;
    float4 f0 = *reinterpret_cast<const float4*>(x + idx);
    float4 f1 = *reinterpret_cast<const float4*>(x + idx + 4);
    short8 v;
    v[0] = (short)f2bf(f0.x); v[1] = (short)f2bf(f0.y);
    v[2] = (short)f2bf(f0.z); v[3] = (short)f2bf(f0.w);
    v[4] = (short)f2bf(f1.x); v[5] = (short)f2bf(f1.y);
    v[6] = (short)f2bf(f1.z); v[7] = (short)f2bf(f1.w);
    *reinterpret_cast<short8*>(xb + idx) = v;
}

// ---------------- Kernel 1: convert+transpose Wqkv (1024x3072 fp32) -> WT (3072x1024 bf16) ----
__global__ void transpose_w(const float* __restrict__ W, u16* __restrict__ WT) {
    __shared__ u16 tile[32][34];
    int nb = blockIdx.x * 32;
    int kb = blockIdx.y * 32;
    int tx = threadIdx.x;   // 0..31
    int ty = threadIdx.y;   // 0..7
    #pragma unroll
    for (int i = 0; i < 32; i += 8)
        tile[ty + i][tx] = f2bf(W[(size_t)(kb + ty + i) * 3072 + nb + tx]);
    __syncthreads();
    #pragma unroll
    for (int i = 0; i < 32; i += 8)
        WT[(size_t)(nb + ty + i) * D_DIM + kb + tx] = tile[tx][ty + i];
}

// ---------------- Kernel 2: 256x256-tile 8-wave phase-split GEMM (8-phase template port) ----
// C[row, col] = sum_k xb[row,k] * WT[col,k] + bqkv[col]
// by<4: q cols -> qb + row-sumsq -> qssq ; by 4..7: k -> kvb + kssq ; by>=8: v -> kvb
//
// Schedule per K-tile (BK=64): 4 quadrant phases of 16 MFMA each, raw s_barrier pairs,
// setprio(1) around MFMA clusters (T5). Staging for tile t+1 front-loaded into phases 1-2
// (4 A-GLL then 4 B-GLL), single vmcnt(0) at end of phase 4 — drained loads are >=2 MFMA
// phases old (race-free with 2 buffers; avoids draining freshly-issued loads).
// LDS: linear dest (GLL requirement) + inverse-swizzled global source + swizzled read
// (16B-slot: slot(row,g) = row*8 + (g ^ (row&7)) — measured 0 bank conflicts).

#define TILE_BODY(ARD0, ARD1, BRD0, BRD1, DO_STG, SA, SB) do {                    \
    short8 aF[4][2], bN0[2][2], bN1[2][2];                                        \
    /* phase 1: (mh0, nh0) -- 12 ds_read + 4 A-GLL */                             \
    _Pragma("unroll")                                                             \
    for (int mt = 0; mt < 4; ++mt) {                                              \
        aF[mt][0] = *reinterpret_cast<const short8*>((ARD0) + mt * 1024);         \
        aF[mt][1] = *reinterpret_cast<const short8*>((ARD1) + mt * 1024);         \
    }                                                                             \
    _Pragma("unroll")                                                             \
    for (int nt = 0; nt < 2; ++nt) {                                              \
        bN0[nt][0] = *reinterpret_cast<const short8*>((BRD0) + nt * 1024);        \
        bN0[nt][1] = *reinterpret_cast<const short8*>((BRD1) + nt * 1024);        \
    }                                                                             \
    if (DO_STG) {                                                                 \
        GLL16(aptr[0], (SA)[0]); GLL16(aptr[1], (SA)[1]);                         \
        GLL16(aptr[2], (SA)[2]); GLL16(aptr[3], (SA)[3]);                         \
        aptr[0] += 64; aptr[1] += 64; aptr[2] += 64; aptr[3] += 64;               \
    }                                                                             \
    __builtin_amdgcn_s_barrier(); __builtin_amdgcn_sched_barrier(0);              \
    __builtin_amdgcn_s_setprio(1);                                                \
    _Pragma("unroll")                                                             \
    for (int mt = 0; mt < 4; ++mt)                                                \
        _Pragma("unroll")                                                         \
        for (int nt = 0; nt < 2; ++nt) {                                          \
            acc[mt][nt] = __builtin_amdgcn_mfma_f32_16x16x32_bf16(                \
                aF[mt][0], bN0[nt][0], acc[mt][nt], 0, 0, 0);                     \
            acc[mt][nt] = __builtin_amdgcn_mfma_f32_16x16x32_bf16(                \
                aF[mt][1], bN0[nt][1], acc[mt][nt], 0, 0, 0);                     \
        }                                                                         \
    __builtin_amdgcn_s_setprio(0);                                                \
    __builtin_amdgcn_s_barrier(); __builtin_amdgcn_sched_barrier(0);              \
    /* phase 2: (mh0, nh1) -- 4 ds_read + 4 B-GLL */                              \
    _Pragma("unroll")                                                             \
    for (int nt = 0; nt < 2; ++nt) {                                              \
        bN1[nt][0] = *reinterpret_cast<const short8*>((BRD0) + (2 + nt) * 1024);  \
        bN1[nt][1] = *reinterpret_cast<const short8*>((BRD1) + (2 + nt) * 1024);  \
    }                                                                             \
    if (DO_STG) {                                                                 \
        GLL16(bptr[0], (SB)[0]); GLL16(bptr[1], (SB)[1]);                         \
        GLL16(bptr[2], (SB)[2]); GLL16(bptr[3], (SB)[3]);                         \
        bptr[0] += 64; bptr[1] += 64; bptr[2] += 64; bptr[3] += 64;               \
    }                                                                             \
    __builtin_amdgcn_s_barrier(); __builtin_amdgcn_sched_barrier(0);              \
    __builtin_amdgcn_s_setprio(1);                                                \
    _Pragma("unroll")                                                             \
    for (int mt = 0; mt < 4; ++mt)                                                \
        _Pragma("unroll")                                                         \
        for (int nt = 0; nt < 2; ++nt) {                                          \
            acc[mt][2 + nt] = __builtin_amdgcn_mfma_f32_16x16x32_bf16(            \
                aF[mt][0], bN1[nt][0], acc[mt][2 + nt], 0, 0, 0);                 \
            acc[mt][2 + nt] = __builtin_amdgcn_mfma_f32_16x16x32_bf16(            \
                aF[mt][1], bN1[nt][1], acc[mt][2 + nt], 0, 0, 0);                 \
        }                                                                         \
    __builtin_amdgcn_s_setprio(0);                                                \
    __builtin_amdgcn_s_barrier(); __builtin_amdgcn_sched_barrier(0);              \
    /* phase 3: (mh1, nh0) -- 8 ds_read */                                        \
    _Pragma("unroll")                                                             \
    for (int mt = 0; mt < 4; ++mt) {                                              \
        aF[mt][0] = *reinterpret_cast<const short8*>((ARD0) + 4096 + mt * 1024);  \
        aF[mt][1] = *reinterpret_cast<const short8*>((ARD1) + 4096 + mt * 1024);  \
    }                                                                             \
    __builtin_amdgcn_s_barrier(); __builtin_amdgcn_sched_barrier(0);              \
    __builtin_amdgcn_s_setprio(1);                                                \
    _Pragma("unroll")                                                             \
    for (int mt = 0; mt < 4; ++mt)                                                \
        _Pragma("unroll")                                                         \
        for (int nt = 0; nt < 2; ++nt) {                                          \
            acc[4 + mt][nt] = __builtin_amdgcn_mfma_f32_16x16x32_bf16(            \
                aF[mt][0], bN0[nt][0], acc[4 + mt][nt], 0, 0, 0);                 \
            acc[4 + mt][nt] = __builtin_amdgcn_mfma_f32_16x16x32_bf16(            \
                aF[mt][1], bN0[nt][1], acc[4 + mt][nt], 0, 0, 0);                 \
        }                                                                         \
    __builtin_amdgcn_s_setprio(0);                                                \
    __builtin_amdgcn_s_barrier(); __builtin_amdgcn_sched_barrier(0);              \
    /* phase 4: (mh1, nh1) -- pure MFMA, then boundary vmcnt+barrier */           \
    __builtin_amdgcn_s_setprio(1);                                                \
    _Pragma("unroll")                                                             \
    for (int mt = 0; mt < 4; ++mt)                                                \
        _Pragma("unroll")                                                         \
        for (int nt = 0; nt < 2; ++nt) {                                          \
            acc[4 + mt][2 + nt] = __builtin_amdgcn_mfma_f32_16x16x32_bf16(        \
                aF[mt][0], bN1[nt][0], acc[4 + mt][2 + nt], 0, 0, 0);             \
            acc[4 + mt][2 + nt] = __builtin_amdgcn_mfma_f32_16x16x32_bf16(        \
                aF[mt][1], bN1[nt][1], acc[4 + mt][2 + nt], 0, 0, 0);             \
        }                                                                         \
    __builtin_amdgcn_s_setprio(0);                                                \
    if (DO_STG) { asm volatile("s_waitcnt vmcnt(0)" ::: "memory"); }              \
    __builtin_amdgcn_s_barrier(); __builtin_amdgcn_sched_barrier(0);              \
} while (0)

__global__ __launch_bounds__(512, 2)
void gemm_k(const u16* __restrict__ xb, const u16* __restrict__ WT,
            const float* __restrict__ bqkv,
            u16* __restrict__ qb, u16* __restrict__ kvb,
            float* __restrict__ qssq, float* __restrict__ kssq)
{
    // double-buffered 256x64 bf16 tiles, 16B-slot swizzled: slot(row,g)=row*8+(g^(row&7))
    __shared__ __align__(16) u16 a_sh[2][256 * 64];
    __shared__ __align__(16) u16 b_sh[2][256 * 64];

    const int tid  = threadIdx.x;
    const int lane = tid & 63;
    const int w    = tid >> 6;      // wave 0..7
    const int l15  = lane & 15;
    const int quad = lane >> 4;     // 0..3
    const int wm   = w >> 2;        // 0..1  (M half)
    const int wn   = w & 3;         // 0..3  (N quarter)

    // bijective XCD swizzle: 1536 blocks, 192 contiguous (bx,by) per XCD
    const int flat = blockIdx.x;
    const int swz  = (flat & 7) * 192 + (flat >> 3);
    const int bx   = swz & 127;     // 0..127 (M)
    const int by   = swz >> 7;      // 0..11  (N)
    const int r0   = bx * 256;
    const int c0   = by * 256;

    // staging: thread stages 16B slots s = w*256 + i*64 + lane, i=0..3, per operand
    const u16* aptr[4];
    const u16* bptr[4];
    u16* alds0[4]; u16* alds1[4];
    u16* blds0[4]; u16* blds1[4];
    #pragma unroll
    for (int i = 0; i < 4; ++i) {
        int s    = w * 256 + i * 64 + lane;
        int row  = s >> 3;
        int gsrc = (s & 7) ^ (row & 7);         // inverse-swizzled global source
        aptr[i]  = xb + (size_t)(r0 + row) * D_DIM + gsrc * 8;
        bptr[i]  = WT + (size_t)(c0 + row) * D_DIM + gsrc * 8;
        alds0[i] = &a_sh[0][(w * 256 + i * 64) * 8];   // wave-uniform linear dest
        alds1[i] = &a_sh[1][(w * 256 + i * 64) * 8];
        blds0[i] = &b_sh[0][(w * 256 + i * 64) * 8];
        blds1[i] = &b_sh[1][(w * 256 + i * 64) * 8];
    }

    // fragment read bases (row&7 == l15&7 since all row offsets are multiples of 16)
    const int g0    = quad ^ (l15 & 7);
    const int aoff0 = (wm * 128 + l15) * 64 + g0 * 8;
    const int aoff1 = (wm * 128 + l15) * 64 + (g0 ^ 4) * 8;
    const int boff0 = (wn * 64 + l15) * 64 + g0 * 8;
    const int boff1 = (wn * 64 + l15) * 64 + (g0 ^ 4) * 8;
    const u16* const aRb0_0 = &a_sh[0][aoff0];
    const u16* const aRb0_1 = &a_sh[0][aoff1];
    const u16* const aRb1_0 = &a_sh[1][aoff0];
    const u16* const aRb1_1 = &a_sh[1][aoff1];
    const u16* const bRb0_0 = &b_sh[0][boff0];
    const u16* const bRb0_1 = &b_sh[0][boff1];
    const u16* const bRb1_0 = &b_sh[1][boff0];
    const u16* const bRb1_1 = &b_sh[1][boff1];

    f32x4 acc[8][4];
    #pragma unroll
    for (int mi = 0; mi < 8; ++mi)
        #pragma unroll
        for (int nt = 0; nt < 4; ++nt) acc[mi][nt] = (f32x4)(0.0f);

    // prologue: stage K-tile 0 into buf0, drain, barrier
    #pragma unroll
    for (int i = 0; i < 4; ++i) { GLL16(aptr[i], alds0[i]); }
    #pragma unroll
    for (int i = 0; i < 4; ++i) { GLL16(bptr[i], blds0[i]); }
    #pragma unroll
    for (int i = 0; i < 4; ++i) { aptr[i] += 64; bptr[i] += 64; }
    asm volatile("s_waitcnt vmcnt(0)" ::: "memory");
    __builtin_amdgcn_s_barrier();
    __builtin_amdgcn_sched_barrier(0);

    // K = 1024 -> 16 K-tiles; tiles 0..13 in 7 double iterations, then 14 (stage 15), 15 (drain)
    #pragma unroll 1
    for (int it = 0; it < 7; ++it) {
        TILE_BODY(aRb0_0, aRb0_1, bRb0_0, bRb0_1, 1, alds1, blds1);
        TILE_BODY(aRb1_0, aRb1_1, bRb1_0, bRb1_1, 1, alds0, blds0);
    }
    TILE_BODY(aRb0_0, aRb0_1, bRb0_0, bRb0_1, 1, alds1, blds1);
    TILE_BODY(aRb1_0, aRb1_1, bRb1_0, bRb1_1, 0, alds0, blds0);

    // ---- epilogue: bias ----
    float bcol[4];
    #pragma unroll
    for (int nt = 0; nt < 4; ++nt)
        bcol[nt] = bqkv[c0 + wn * 64 + nt * 16 + l15];
    #pragma unroll
    for (int mi = 0; mi < 8; ++mi)
        #pragma unroll
        for (int nt = 0; nt < 4; ++nt)
            #pragma unroll
            for (int rg = 0; rg < 4; ++rg) acc[mi][nt][rg] += bcol[nt];

    // ---- row sum-of-squares (q and k blocks only) ----
    if (by < 8) {
        float* ssq = (by < 4) ? qssq : kssq;
        #pragma unroll
        for (int mi = 0; mi < 8; ++mi)
            #pragma unroll
            for (int rg = 0; rg < 4; ++rg) {
                float s = acc[mi][0][rg] * acc[mi][0][rg]
                        + acc[mi][1][rg] * acc[mi][1][rg]
                        + acc[mi][2][rg] * acc[mi][2][rg]
                        + acc[mi][3][rg] * acc[mi][3][rg];
                #pragma unroll
                for (int m = 1; m < 16; m <<= 1) s += __shfl_xor(s, m, 16);
                if (l15 == 0)
                    atomicAdd(&ssq[r0 + wm * 128 + mi * 16 + quad * 4 + rg], s);
            }
    }

    // ---- store bf16 ----
    u16* dst;
    int ldc, cb;
    if (by < 4) { dst = qb;  ldc = 1024; cb = c0; }
    else        { dst = kvb; ldc = 2048; cb = c0 - 1024; }
    #pragma unroll
    for (int mi = 0; mi < 8; ++mi)
        #pragma unroll
        for (int nt = 0; nt < 4; ++nt) {
            int col = cb + wn * 64 + nt * 16 + l15;
            #pragma unroll
            for (int rg = 0; rg < 4; ++rg) {
                int row = r0 + wm * 128 + mi * 16 + quad * 4 + rg;
                dst[(size_t)row * ldc + col] = f2bf(acc[mi][nt][rg]);
            }
        }
}

// ---------------- Kernel 3: kv[b,d] = sum_t k*v*rsqrt(kssq) ----------------
__global__ void kv_reduce(const u16* __restrict__ kvb, const float* __restrict__ kssq,
                          float* __restrict__ kv)
{
    int d  = threadIdx.x * 8;                  // 128 threads cover 1024 d
    int b  = blockIdx.y;                       // 0..3
    int t0 = blockIdx.x * 64;                  // 128 t-chunks of 64 rows
    float a[8];
    #pragma unroll
    for (int e = 0; e < 8; ++e) a[e] = 0.0f;
    for (int r = 0; r < 64; ++r) {
        int row = b * T_DIM + t0 + r;
        float kin = rsqrtf(kssq[row]);
        short8 k8 = *reinterpret_cast<const short8*>(kvb + (size_t)row * 2048 + d);
        short8 v8 = *reinterpret_cast<const short8*>(kvb + (size_t)row * 2048 + 1024 + d);
        #pragma unroll
        for (int e = 0; e < 8; ++e)
            a[e] += bf2f((u16)k8[e]) * bf2f((u16)v8[e]) * kin;
    }
    #pragma unroll
    for (int e = 0; e < 8; ++e)
        atomicAdd(&kv[b * D_DIM + d + e], a[e]);
}

// ---------------- Kernel 4: out = q*rsqrt(qssq)*kv*scale + bias (fp32) ----------------
__global__ void finalize(const u16* __restrict__ qb, const float* __restrict__ qssq,
                         const float* __restrict__ kv, const float* __restrict__ scale,
                         const float* __restrict__ bias, float* __restrict__ out)
{
    size_t idx = (size_t)blockIdx.x * 256 + threadIdx.x;   // vec8 index
    int row = (int)(idx >> 7);
    int dv  = ((int)idx & 127) * 8;
    int b   = row >> 13;
    float qi = rsqrtf(qssq[row]);
    short8 qv = *reinterpret_cast<const short8*>(qb + (size_t)row * D_DIM + dv);
    const float* kvp = kv + b * D_DIM + dv;
    const float* sp  = scale + dv;
    const float* bp  = bias + dv;
    float4 o0, o1;
    o0.x = bf2f((u16)qv[0]) * qi * kvp[0] * sp[0] + bp[0];
    o0.y = bf2f((u16)qv[1]) * qi * kvp[1] * sp[1] + bp[1];
    o0.z = bf2f((u16)qv[2]) * qi * kvp[2] * sp[2] + bp[2];
    o0.w = bf2f((u16)qv[3]) * qi * kvp[3] * sp[3] + bp[3];
    o1.x = bf2f((u16)qv[4]) * qi * kvp[4] * sp[4] + bp[4];
    o1.y = bf2f((u16)qv[5]) * qi * kvp[5] * sp[5] + bp[5];
    o1.z = bf2f((u16)qv[6]) * qi * kvp[6] * sp[6] + bp[6];
    o1.w = bf2f((u16)qv[7]) * qi * kvp[7] * sp[7] + bp[7];
    float* op = out + (size_t)row * D_DIM + dv;
    *reinterpret_cast<float4*>(op)     = o0;
    *reinterpret_cast<float4*>(op + 4) = o1;
}

extern "C" void kernel_launch(void* const* d_in, const int* in_sizes, int n_in,
                              void* d_out, int out_size, void* d_ws, size_t ws_size,
                              hipStream_t stream) {
    const float* x     = (const float*)d_in[0];
    const float* W     = (const float*)d_in[1];
    const float* bqkv  = (const float*)d_in[2];
    const float* scale = (const float*)d_in[3];
    const float* bias  = (const float*)d_in[4];
    float* out = (float*)d_out;

    // d_out doubles as scratch until finalize: xb (64 MB) + WT (6 MB) < 128 MB
    u16* xb = (u16*)d_out;
    u16* WT = (u16*)((char*)d_out + 67108864);

    char* ws = (char*)d_ws;
    u16*   qb   = (u16*)ws;                         //  67,108,864 B
    u16*   kvb  = (u16*)(ws + 67108864);            // 134,217,728 B
    float* qssq = (float*)(ws + 201326592);         //     131,072 B
    float* kssq = (float*)(ws + 201457664);         //     131,072 B
    float* kv   = (float*)(ws + 201588736);         //      16,384 B

    convert_x  <<<dim3(ROWS * D_DIM / 8 / 256), dim3(256), 0, stream>>>(x, xb);
    transpose_w<<<dim3(96, 32), dim3(32, 8), 0, stream>>>(W, WT);
    hipMemsetAsync(qssq, 0, 131072 + 131072 + 16384, stream);
    gemm_k     <<<dim3(1536), dim3(512), 0, stream>>>(xb, WT, bqkv, qb, kvb, qssq, kssq);
    kv_reduce  <<<dim3(T_DIM / 64, 4), dim3(128), 0, stream>>>(kvb, kssq, kv);
    finalize   <<<dim3(ROWS * (D_DIM / 8) / 256), dim3(256), 0, stream>>>(qb, qssq, kv, scale, bias, out);
}

// Round 2
// 421.200 us; speedup vs baseline: 1.0337x; 1.0337x over previous
//
#include <hip/hip_runtime.h>

typedef unsigned short u16;
typedef __attribute__((ext_vector_type(8))) short short8;
typedef __attribute__((ext_vector_type(4))) float f32x4;

#define D_DIM   1024
#define ROWS    32768   // B*T = 4*8192
#define T_DIM   8192

__device__ __forceinline__ float bf2f(u16 u) {
    union { unsigned int i; float f; } c; c.i = ((unsigned int)u) << 16; return c.f;
}
__device__ __forceinline__ u16 f2bf(float f) {
    union { float f; unsigned int i; } c; c.f = f;
    unsigned int r = c.i + 0x7FFF + ((c.i >> 16) & 1);   // RNE
    return (u16)(r >> 16);
}

#define GLL16(gp, lp) \
    __builtin_amdgcn_global_load_lds((const __attribute__((address_space(1))) void*)(gp), \
                                     (__attribute__((address_space(3))) void*)(lp), 16, 0, 0)

// ---------------- Kernel 0: x fp32 -> xb bf16 ----------------
__global__ void convert_x(const float* __restrict__ x, u16* __restrict__ xb) {
    size_t idx = ((size_t)blockIdx.x * 256 + threadIdx.x) * 8;
    float4 f0 = *reinterpret_cast<const float4*>(x + idx);
    float4 f1 = *reinterpret_cast<const float4*>(x + idx + 4);
    short8 v;
    v[0] = (short)f2bf(f0.x); v[1] = (short)f2bf(f0.y);
    v[2] = (short)f2bf(f0.z); v[3] = (short)f2bf(f0.w);
    v[4] = (short)f2bf(f1.x); v[5] = (short)f2bf(f1.y);
    v[6] = (short)f2bf(f1.z); v[7] = (short)f2bf(f1.w);
    *reinterpret_cast<short8*>(xb + idx) = v;
}

// ---------------- Kernel 1: convert+transpose Wqkv (1024x3072 fp32) -> WT (3072x1024 bf16) ----
__global__ void transpose_w(const float* __restrict__ W, u16* __restrict__ WT) {
    __shared__ u16 tile[32][34];
    int nb = blockIdx.x * 32;
    int kb = blockIdx.y * 32;
    int tx = threadIdx.x;   // 0..31
    int ty = threadIdx.y;   // 0..7
    #pragma unroll
    for (int i = 0; i < 32; i += 8)
        tile[ty + i][tx] = f2bf(W[(size_t)(kb + ty + i) * 3072 + nb + tx]);
    __syncthreads();
    #pragma unroll
    for (int i = 0; i < 32; i += 8)
        WT[(size_t)(nb + ty + i) * D_DIM + kb + tx] = tile[tx][ty + i];
}

// ---------------- Kernel 2: 256x256-tile, 4-slot K=32 ring, counted-vmcnt pipeline (T3+T4+T5) ----
// C[row, col] = sum_k xb[row,k] * WT[col,k] + bqkv[col]
// K = 1024 -> 32 slots of K=32. LDS ring of 4 slots (A 16KB + B 16KB each) = 128 KiB.
// Stage 3 slots ahead; residency wait for slot s+1 is vmcnt(8) at the END of slot s's
// second phase (loads for s+1 were issued 3 slots = 6 phases earlier), followed by the
// closing barrier -> cross-wave certified. vmcnt never drains to 0 until the tail (T4).
// Each slot: 2 phases x {ds_read frags, 2 GLL, barrier, setprio(1), 16 MFMA, setprio(0), barrier}.
// Slot layout: row-major 256x32 u16, 4x16B groups/row, XOR swizzle g' = g ^ (row&3):
// fragment ds_read_b128 hits 8 lanes per 16B-class x 8 classes = 8-cycle minimum (conflict-free).

#define PHASE_A(R, SR, STG) do {                                                  \
    short8 aF[4];                                                                 \
    _Pragma("unroll")                                                             \
    for (int mt = 0; mt < 4; ++mt)                                                \
        aF[mt] = *reinterpret_cast<const short8*>(&a_sh[R][aRd + mt * 512]);      \
    _Pragma("unroll")                                                             \
    for (int nt = 0; nt < 4; ++nt)                                                \
        bN[nt] = *reinterpret_cast<const short8*>(&b_sh[R][bRd + nt * 512]);      \
    if (STG) {                                                                    \
        GLL16(aPtr0, &a_sh[SR][aDst0]); GLL16(aPtr1, &a_sh[SR][aDst1]);           \
        aPtr0 += 32; aPtr1 += 32;                                                 \
    }                                                                             \
    __builtin_amdgcn_s_barrier(); __builtin_amdgcn_sched_barrier(0);              \
    __builtin_amdgcn_s_setprio(1);                                                \
    _Pragma("unroll")                                                             \
    for (int mt = 0; mt < 4; ++mt)                                                \
        _Pragma("unroll")                                                         \
        for (int nt = 0; nt < 4; ++nt)                                            \
            acc[mt][nt] = __builtin_amdgcn_mfma_f32_16x16x32_bf16(                \
                aF[mt], bN[nt], acc[mt][nt], 0, 0, 0);                            \
    __builtin_amdgcn_s_setprio(0);                                                \
    __builtin_amdgcn_s_barrier(); __builtin_amdgcn_sched_barrier(0);              \
} while (0)

#define PHASE_B(R, SR, STG, VM) do {                                              \
    short8 aF[4];                                                                 \
    _Pragma("unroll")                                                             \
    for (int mt = 0; mt < 4; ++mt)                                                \
        aF[mt] = *reinterpret_cast<const short8*>(&a_sh[R][aRd + 2048 + mt * 512]); \
    if (STG) {                                                                    \
        GLL16(bPtr0, &b_sh[SR][aDst0]); GLL16(bPtr1, &b_sh[SR][aDst1]);           \
        bPtr0 += 32; bPtr1 += 32;                                                 \
    }                                                                             \
    if ((VM) == 8)      asm volatile("s_waitcnt vmcnt(8)" ::: "memory");          \
    else if ((VM) == 4) asm volatile("s_waitcnt vmcnt(4)" ::: "memory");          \
    else if ((VM) == 0) asm volatile("s_waitcnt vmcnt(0)" ::: "memory");          \
    __builtin_amdgcn_s_barrier(); __builtin_amdgcn_sched_barrier(0);              \
    __builtin_amdgcn_s_setprio(1);                                                \
    _Pragma("unroll")                                                             \
    for (int mt = 0; mt < 4; ++mt)                                                \
        _Pragma("unroll")                                                         \
        for (int nt = 0; nt < 4; ++nt)                                            \
            acc[4 + mt][nt] = __builtin_amdgcn_mfma_f32_16x16x32_bf16(            \
                aF[mt], bN[nt], acc[4 + mt][nt], 0, 0, 0);                        \
    __builtin_amdgcn_s_setprio(0);                                                \
    __builtin_amdgcn_s_barrier(); __builtin_amdgcn_sched_barrier(0);              \
} while (0)

__global__ __launch_bounds__(512, 2)
void gemm_k(const u16* __restrict__ xb, const u16* __restrict__ WT,
            const float* __restrict__ bqkv,
            u16* __restrict__ qb, u16* __restrict__ kvb,
            float* __restrict__ qssq, float* __restrict__ kssq)
{
    // 4-slot ring: each slot 256 rows x 32 k (u16), 8192 u16 = 16 KB per operand
    __shared__ __align__(16) u16 a_sh[4][8192];
    __shared__ __align__(16) u16 b_sh[4][8192];

    const int tid  = threadIdx.x;
    const int lane = tid & 63;
    const int w    = tid >> 6;      // wave 0..7
    const int l15  = lane & 15;
    const int quad = lane >> 4;     // 0..3
    const int wm   = w >> 2;        // 0..1  (M half)
    const int wn   = w & 3;         // 0..3  (N quarter)

    // bijective XCD swizzle: 1536 blocks, 192 contiguous (bx,by) per XCD
    const int flat = blockIdx.x;
    const int swz  = (flat & 7) * 192 + (flat >> 3);
    const int bx   = swz & 127;     // 0..127 (M)
    const int by   = swz >> 7;      // 0..11  (N)
    const int r0   = bx * 256;
    const int c0   = by * 256;

    // ---- staging addresses ----
    // thread stages 16B groups sidx = w*128 + i*64 + lane (i=0,1) of each slot.
    // group -> (row = sidx>>2, g' = sidx&3); source k-group gsrc = g' ^ (row&3).
    const int row0  = w * 32 + (lane >> 2);          // sidx0>>2
    const int gsrc  = (lane & 3) ^ (row0 & 3);       // same for i=0,1 (rows differ by 16)
    const u16* aPtr0 = xb + (size_t)(r0 + row0) * D_DIM + gsrc * 8;
    const u16* aPtr1 = xb + (size_t)(r0 + row0 + 16) * D_DIM + gsrc * 8;
    const u16* bPtr0 = WT + (size_t)(c0 + row0) * D_DIM + gsrc * 8;
    const u16* bPtr1 = WT + (size_t)(c0 + row0 + 16) * D_DIM + gsrc * 8;
    const int aDst0 = w * 1024;          // (w*128 + 0*64) * 8  u16, wave-uniform linear dest
    const int aDst1 = w * 1024 + 512;    // (w*128 + 1*64) * 8

    // ---- fragment read offsets (u16 index within a slot) ----
    // A row = wm*128 + mh*64 + mt*16 + l15 ; B row = wn*64 + nt*16 + l15 ; row&3 == l15&3
    const int gq  = (quad ^ (l15 & 3)) * 8;
    const int aRd = (wm * 128 + l15) * 32 + gq;      // +mt*512, +2048 for mh=1
    const int bRd = (wn * 64 + l15) * 32 + gq;       // +nt*512

    f32x4 acc[8][4];
    #pragma unroll
    for (int mi = 0; mi < 8; ++mi)
        #pragma unroll
        for (int nt = 0; nt < 4; ++nt) acc[mi][nt] = (f32x4)(0.0f);

    short8 bN[4];

    // ---- prologue: stage slots 0,1,2 (ring 0,1,2), 4 GLL each in slot order ----
    GLL16(aPtr0, &a_sh[0][aDst0]); GLL16(aPtr1, &a_sh[0][aDst1]);
    GLL16(bPtr0, &b_sh[0][aDst0]); GLL16(bPtr1, &b_sh[0][aDst1]);
    aPtr0 += 32; aPtr1 += 32; bPtr0 += 32; bPtr1 += 32;
    GLL16(aPtr0, &a_sh[1][aDst0]); GLL16(aPtr1, &a_sh[1][aDst1]);
    GLL16(bPtr0, &b_sh[1][aDst0]); GLL16(bPtr1, &b_sh[1][aDst1]);
    aPtr0 += 32; aPtr1 += 32; bPtr0 += 32; bPtr1 += 32;
    GLL16(aPtr0, &a_sh[2][aDst0]); GLL16(aPtr1, &a_sh[2][aDst1]);
    GLL16(bPtr0, &b_sh[2][aDst0]); GLL16(bPtr1, &b_sh[2][aDst1]);
    aPtr0 += 32; aPtr1 += 32; bPtr0 += 32; bPtr1 += 32;
    asm volatile("s_waitcnt vmcnt(8)" ::: "memory");   // slot 0 resident (own loads)
    __builtin_amdgcn_s_barrier();                      // ... and everyone else's
    __builtin_amdgcn_sched_barrier(0);

    // ---- main loop: slots 0..27 (ring 0..3), each stages slot s+3, waits slot s+1 ----
    #pragma unroll 1
    for (int it = 0; it < 7; ++it) {
        PHASE_A(0, 3, 1); PHASE_B(0, 3, 1, 8);
        PHASE_A(1, 0, 1); PHASE_B(1, 0, 1, 8);
        PHASE_A(2, 1, 1); PHASE_B(2, 1, 1, 8);
        PHASE_A(3, 2, 1); PHASE_B(3, 2, 1, 8);
    }
    // ---- tail: slots 28..31 ----
    PHASE_A(0, 3, 1); PHASE_B(0, 3, 1, 8);   // slot 28: stage slot 31, wait slot 29
    PHASE_A(1, 0, 0); PHASE_B(1, 0, 0, 4);   // slot 29: wait slot 30
    PHASE_A(2, 0, 0); PHASE_B(2, 0, 0, 0);   // slot 30: wait slot 31
    PHASE_A(3, 0, 0); PHASE_B(3, 0, 0, -1);  // slot 31
    __builtin_amdgcn_s_barrier();

    // ---- epilogue: bias ----
    float bcol[4];
    #pragma unroll
    for (int nt = 0; nt < 4; ++nt)
        bcol[nt] = bqkv[c0 + wn * 64 + nt * 16 + l15];
    #pragma unroll
    for (int mi = 0; mi < 8; ++mi)
        #pragma unroll
        for (int nt = 0; nt < 4; ++nt)
            #pragma unroll
            for (int rg = 0; rg < 4; ++rg) acc[mi][nt][rg] += bcol[nt];

    // ---- row sum-of-squares (q and k blocks only) ----
    if (by < 8) {
        float* ssq = (by < 4) ? qssq : kssq;
        #pragma unroll
        for (int mi = 0; mi < 8; ++mi)
            #pragma unroll
            for (int rg = 0; rg < 4; ++rg) {
                float s = acc[mi][0][rg] * acc[mi][0][rg]
                        + acc[mi][1][rg] * acc[mi][1][rg]
                        + acc[mi][2][rg] * acc[mi][2][rg]
                        + acc[mi][3][rg] * acc[mi][3][rg];
                #pragma unroll
                for (int m = 1; m < 16; m <<= 1) s += __shfl_xor(s, m, 16);
                if (l15 == 0)
                    atomicAdd(&ssq[r0 + wm * 128 + mi * 16 + quad * 4 + rg], s);
            }
    }

    // ---- store bf16 ----
    u16* dst;
    int ldc, cb;
    if (by < 4) { dst = qb;  ldc = 1024; cb = c0; }
    else        { dst = kvb; ldc = 2048; cb = c0 - 1024; }
    #pragma unroll
    for (int mi = 0; mi < 8; ++mi)
        #pragma unroll
        for (int nt = 0; nt < 4; ++nt) {
            int col = cb + wn * 64 + nt * 16 + l15;
            #pragma unroll
            for (int rg = 0; rg < 4; ++rg) {
                int row = r0 + wm * 128 + mi * 16 + quad * 4 + rg;
                dst[(size_t)row * ldc + col] = f2bf(acc[mi][nt][rg]);
            }
        }
}

// ---------------- Kernel 3: kv[b,d] = sum_t k*v*rsqrt(kssq) ----------------
__global__ void kv_reduce(const u16* __restrict__ kvb, const float* __restrict__ kssq,
                          float* __restrict__ kv)
{
    int d  = threadIdx.x * 8;                  // 128 threads cover 1024 d
    int b  = blockIdx.y;                       // 0..3
    int t0 = blockIdx.x * 64;                  // 128 t-chunks of 64 rows
    float a[8];
    #pragma unroll
    for (int e = 0; e < 8; ++e) a[e] = 0.0f;
    for (int r = 0; r < 64; ++r) {
        int row = b * T_DIM + t0 + r;
        float kin = rsqrtf(kssq[row]);
        short8 k8 = *reinterpret_cast<const short8*>(kvb + (size_t)row * 2048 + d);
        short8 v8 = *reinterpret_cast<const short8*>(kvb + (size_t)row * 2048 + 1024 + d);
        #pragma unroll
        for (int e = 0; e < 8; ++e)
            a[e] += bf2f((u16)k8[e]) * bf2f((u16)v8[e]) * kin;
    }
    #pragma unroll
    for (int e = 0; e < 8; ++e)
        atomicAdd(&kv[b * D_DIM + d + e], a[e]);
}

// ---------------- Kernel 4: out = q*rsqrt(qssq)*kv*scale + bias (fp32) ----------------
__global__ void finalize(const u16* __restrict__ qb, const float* __restrict__ qssq,
                         const float* __restrict__ kv, const float* __restrict__ scale,
                         const float* __restrict__ bias, float* __restrict__ out)
{
    size_t idx = (size_t)blockIdx.x * 256 + threadIdx.x;   // vec8 index
    int row = (int)(idx >> 7);
    int dv  = ((int)idx & 127) * 8;
    int b   = row >> 13;
    float qi = rsqrtf(qssq[row]);
    short8 qv = *reinterpret_cast<const short8*>(qb + (size_t)row * D_DIM + dv);
    const float* kvp = kv + b * D_DIM + dv;
    const float* sp  = scale + dv;
    const float* bp  = bias + dv;
    float4 o0, o1;
    o0.x = bf2f((u16)qv[0]) * qi * kvp[0] * sp[0] + bp[0];
    o0.y = bf2f((u16)qv[1]) * qi * kvp[1] * sp[1] + bp[1];
    o0.z = bf2f((u16)qv[2]) * qi * kvp[2] * sp[2] + bp[2];
    o0.w = bf2f((u16)qv[3]) * qi * kvp[3] * sp[3] + bp[3];
    o1.x = bf2f((u16)qv[4]) * qi * kvp[4] * sp[4] + bp[4];
    o1.y = bf2f((u16)qv[5]) * qi * kvp[5] * sp[5] + bp[5];
    o1.z = bf2f((u16)qv[6]) * qi * kvp[6] * sp[6] + bp[6];
    o1.w = bf2f((u16)qv[7]) * qi * kvp[7] * sp[7] + bp[7];
    float* op = out + (size_t)row * D_DIM + dv;
    *reinterpret_cast<float4*>(op)     = o0;
    *reinterpret_cast<float4*>(op + 4) = o1;
}

extern "C" void kernel_launch(void* const* d_in, const int* in_sizes, int n_in,
                              void* d_out, int out_size, void* d_ws, size_t ws_size,
                              hipStream_t stream) {
    const float* x     = (const float*)d_in[0];
    const float* W     = (const float*)d_in[1];
    const float* bqkv  = (const float*)d_in[2];
    const float* scale = (const float*)d_in[3];
    const float* bias  = (const float*)d_in[4];
    float* out = (float*)d_out;

    // d_out doubles as scratch until finalize: xb (64 MB) + WT (6 MB) < 128 MB
    u16* xb = (u16*)d_out;
    u16* WT = (u16*)((char*)d_out + 67108864);

    char* ws = (char*)d_ws;
    u16*   qb   = (u16*)ws;                         //  67,108,864 B
    u16*   kvb  = (u16*)(ws + 67108864);            // 134,217,728 B
    float* qssq = (float*)(ws + 201326592);         //     131,072 B
    float* kssq = (float*)(ws + 201457664);         //     131,072 B
    float* kv   = (float*)(ws + 201588736);         //      16,384 B

    convert_x  <<<dim3(ROWS * D_DIM / 8 / 256), dim3(256), 0, stream>>>(x, xb);
    transpose_w<<<dim3(96, 32), dim3(32, 8), 0, stream>>>(W, WT);
    hipMemsetAsync(qssq, 0, 131072 + 131072 + 16384, stream);
    gemm_k     <<<dim3(1536), dim3(512), 0, stream>>>(xb, WT, bqkv, qb, kvb, qssq, kssq);
    kv_reduce  <<<dim3(T_DIM / 64, 4), dim3(128), 0, stream>>>(kvb, kssq, kv);
    finalize   <<<dim3(ROWS * (D_DIM / 8) / 256), dim3(256), 0, stream>>>(qb, qssq, kv, scale, bias, out);
}